// Round 15
// baseline (97.448 us; speedup 1.0000x reference)
//
#include <hip/hip_runtime.h>
#include <math.h>

// MarginDevianceLoss: N=4096, D=256, K=8, targets = i/8.
// Outputs: [loss, prec, pos_d, neg_d] fp32.
//
// R15 = R14 (97.3 us) with the stats dispatch folded into gemm2's prologue:
// gemm2 runs after gemm1 completes, so each gemm2 block computes inter/thresh
// for its own 128 i-rows from gemm1's partials (R13-verified math; redundant
// x32 across by — ~16 KB coalesced L2 reads/block, hidden behind A loads).
// by==0 blocks also write posLoss/rowPsum/rowNsum for finalAB.
// Dispatches: convert -> gemm1 -> gemm2(+stats) -> finalAB  (4 total).
// Kept lessons: frag-major bf16 Xf + glds B-staging (R11); no inline fp32
// staging (R12); no big atomic fan-in / grid barriers (R7/R13).

#define NROWS 4096
#define DIM   256
#define KCLS  8
#define NJB   32     // j-blocks = partials per row

typedef __bf16 bf16x8 __attribute__((ext_vector_type(8)));
typedef float  f32x4  __attribute__((ext_vector_type(4)));

// log(1+exp(z)) = max(z,0) + ln2 * log2(1 + exp2(-|z|*log2e));
// log2(1+u), u in (0,1], quartic fit (abs err <= ~4e-4).
__device__ __forceinline__ float softplus_poly(float z) {
    float u = __builtin_exp2f(-1.4426950408889634f * __builtin_fabsf(z));
    float p = u * (1.4426950f + u * (-0.6949650f + u * (0.3454302f + u * -0.0931600f)));
    return fmaf(p, 0.6931471805599453f, fmaxf(z, 0.f));
}

__device__ __forceinline__ unsigned int pack_bf2(float a, float b) {
    unsigned int ua = __float_as_uint(a);
    unsigned int ub = __float_as_uint(b);
    ua = (ua + 0x7FFFu + ((ua >> 16) & 1u)) >> 16;   // RNE
    ub = (ub + 0x7FFFu + ((ub >> 16) & 1u)) >> 16;
    return ua | (ub << 16);
}

__device__ __forceinline__ void glds16(const unsigned short* g, unsigned short* l) {
    // HW: each lane reads 16 B at its own g; LDS dest = uniform l + lane*16.
    __builtin_amdgcn_global_load_lds(
        (const __attribute__((address_space(1))) void*)g,
        (__attribute__((address_space(3))) void*)l, 16, 0, 0);
}

// X (fp32 row-major) -> Xf (bf16 fragment-major):
// Xf[((tile*8 + kf)*64 + lane)*8 + e] = X[tile*16 + (lane&15)][kf*32 + (lane>>4)*8 + e]
// Also zeroes the finalAB done-counter (used 2 dispatches later).
__global__ __launch_bounds__(256)
void convert_kernel(const float* __restrict__ X, unsigned short* __restrict__ Xf,
                    unsigned int* __restrict__ counter)
{
    int v = blockIdx.x * 256 + threadIdx.x;    // 131072 fragment-slices of 16 B
    if (v == 0) *counter = 0u;
    int tile = v >> 9;
    int kf   = (v >> 6) & 7;
    int lane = v & 63;
    int row  = tile * 16 + (lane & 15);
    int c4   = kf * 8 + (lane >> 4) * 2;       // col/4
    const float4* X4 = reinterpret_cast<const float4*>(X);
    float4 a = X4[row * 64 + c4];
    float4 b = X4[row * 64 + c4 + 1];
    uint4 o;
    o.x = pack_bf2(a.x, a.y);
    o.y = pack_bf2(a.z, a.w);
    o.z = pack_bf2(b.x, b.y);
    o.w = pack_bf2(b.z, b.w);
    reinterpret_cast<uint4*>(Xf)[v] = o;
}

// Grid (32,32). Block: 4 waves; wave w -> i-tiles {bx*8+w*2, +1} (A cached in
// regs, K=256). All waves sweep j-tiles [by*8,+8); B staged via LDS
// (global_load_lds, double-buffered, 2 frags/wave/tile).
// PASS 1 (STATS=1): sum/sumsq epilogue + diag classSim -> float4 partials.
// PASS 2 (STATS=0): prologue computes per-row inter/thresh from pass-1
//   partials (LDS broadcast; by==0 also writes posLoss/psum/nsum), then
//   branchless filter + poly-softplus -> cnt/nls partials.
template<int STATS>
__global__ __launch_bounds__(256)
void gemm_pass_kernel(const unsigned short* __restrict__ Xf,
                      const float* __restrict__ sumPart,   // in  (pass 2)
                      const float* __restrict__ sqPart,    // in  (pass 2)
                      float* __restrict__ classSim,        // out p1 / in p2
                      float* __restrict__ outPartA,        // sumPart / cntPart
                      float* __restrict__ outPartB,        // sqPart  / nlsPart
                      float* __restrict__ posLossA,
                      float* __restrict__ rowPsum,
                      float* __restrict__ rowNsum)
{
    __shared__ __align__(16) unsigned short Bs[2][8][512];   // 2 x 8 KB
    __shared__ float interL[128], threshL[128];

    const int t    = threadIdx.x;
    const int lane = t & 63;
    const int wave = t >> 6;
    const int quad = lane >> 4;
    const int n16  = lane & 15;
    const int it0  = blockIdx.x * 8 + wave * 2;
    const int i0   = it0 * 16;
    const int j0   = blockIdx.y * 128;
    const int jt0  = blockIdx.y * 8;
    const bool diag = (blockIdx.x == blockIdx.y);

    // A fragments: 2 i-tiles x 8 k-frags, coalesced 1-KB global loads
    bf16x8 afrag[2][8];
    #pragma unroll
    for (int tt = 0; tt < 2; ++tt) {
        const unsigned short* ap = Xf + ((size_t)(it0 + tt) * 8) * 512 + lane * 8;
        #pragma unroll
        for (int kf = 0; kf < 8; ++kf)
            afrag[tt][kf] = *reinterpret_cast<const bf16x8*>(ap + kf * 512);
    }

    // ---- pass-2 prologue: stats for this block's 128 i-rows ----
    if constexpr (!STATS) {
        if (t < 128) {
            const int i = blockIdx.x * 128 + t;
            const int self = i & 7;
            float S = 0.f, SQ = 0.f;
            #pragma unroll
            for (int b = 0; b < NJB; ++b) {
                S  += sumPart[b * NROWS + i];
                SQ += sqPart[b * NROWS + i];
            }
            float4 c0 = reinterpret_cast<const float4*>(classSim)[i * 2];
            float4 c1 = reinterpret_cast<const float4*>(classSim)[i * 2 + 1];
            float cs[KCLS] = {c0.x, c0.y, c0.z, c0.w, c1.x, c1.y, c1.z, c1.w};
            float sii = cs[self];
            float psum = 0.f, psq = 0.f, pmin = 1e30f;
            #pragma unroll
            for (int m = 0; m < KCLS; ++m) {
                if (m != self) {
                    psum += cs[m];
                    psq  += cs[m] * cs[m];
                    pmin  = fminf(pmin, cs[m]);
                }
            }
            const float p = (float)(KCLS - 1);            // 7
            const float mneg = (float)(NROWS - KCLS);     // 4088
            float nsum = S - psum - sii;
            float nsq  = SQ - psq - sii * sii;
            float pmean = psum / p;
            float pstd  = sqrtf(fmaxf(psq / p - pmean * pmean, 0.f));
            float nmean = nsum / mneg;
            float nstd  = sqrtf(fmaxf(nsq / mneg - nmean * nmean, 0.f));
            float inter = 0.8f * (nstd * pmean + pstd * nmean) / (pstd + nstd) + 0.1f;
            interL[t]  = inter;
            threshL[t] = pmin - 0.05f;
            if (blockIdx.y == 0) {                  // single-writer outputs
                float pl = 0.f;
                #pragma unroll
                for (int m = 0; m < KCLS; ++m) {
                    if (m != self) pl += softplus_poly(-10.f * (cs[m] - inter));
                }
                posLossA[i] = pl * (0.2f / p);
                rowPsum[i]  = psum;
                rowNsum[i]  = nsum;
            }
        }
    }

    // stage B frags for j-tile jt into buffer buf: wave w loads frags 2w,2w+1
    auto stage = [&](int buf, int jt) {
        const unsigned short* src =
            Xf + ((size_t)(jt0 + jt) * 8 + wave * 2) * 512 + lane * 8;
        glds16(src,       &Bs[buf][wave * 2][0]);
        glds16(src + 512, &Bs[buf][wave * 2 + 1][0]);
    };

    stage(0, 0);
    __syncthreads();    // drains glds AND publishes interL/threshL

    float accA[2][4] = {};       // sI / cnt
    float accB[2][4] = {};       // sqI / nls
    float c40[2][4], threshR[2][4];
    int   icls[2];
    if constexpr (!STATS) {
        #pragma unroll
        for (int tt = 0; tt < 2; ++tt) {
            icls[tt] = (i0 + tt * 16 + quad * 4) >> 3;
            int lbase = wave * 32 + tt * 16 + quad * 4;   // local row in block
            #pragma unroll
            for (int r = 0; r < 4; ++r) {
                c40[tt][r]     = -40.f * interL[lbase + r];
                threshR[tt][r] = threshL[lbase + r];
            }
        }
    }

    int buf = 0;
    #pragma unroll 1
    for (int jt = 0; jt < 8; ++jt) {
        if (jt < 7) stage(buf ^ 1, jt + 1);

        bf16x8 bfr[8];
        #pragma unroll
        for (int kf = 0; kf < 8; ++kf)
            bfr[kf] = *reinterpret_cast<const bf16x8*>(&Bs[buf][kf][lane * 8]);

        f32x4 ac[2] = {{0.f, 0.f, 0.f, 0.f}, {0.f, 0.f, 0.f, 0.f}};
        #pragma unroll
        for (int kf = 0; kf < 8; ++kf) {
            ac[0] = __builtin_amdgcn_mfma_f32_16x16x32_bf16(afrag[0][kf], bfr[kf], ac[0], 0, 0, 0);
            ac[1] = __builtin_amdgcn_mfma_f32_16x16x32_bf16(afrag[1][kf], bfr[kf], ac[1], 0, 0, 0);
        }

        if constexpr (STATS) {
            #pragma unroll
            for (int tt = 0; tt < 2; ++tt)
                #pragma unroll
                for (int r = 0; r < 4; ++r) {
                    float s = ac[tt][r];
                    accA[tt][r] += s;
                    accB[tt][r] = fmaf(s, s, accB[tt][r]);
                }
            if (diag) {                    // wave-uniform: 32/1024 blocks
                int j = j0 + jt * 16 + n16;
                #pragma unroll
                for (int tt = 0; tt < 2; ++tt)
                    #pragma unroll
                    for (int r = 0; r < 4; ++r) {
                        int i = i0 + tt * 16 + quad * 4 + r;
                        if (((i ^ j) >> 3) == 0)
                            classSim[i * KCLS + (j & 7)] = ac[tt][r];
                    }
            }
        } else {
            const int jcls = (j0 + jt * 16 + n16) >> 3;
            #pragma unroll
            for (int tt = 0; tt < 2; ++tt) {
                const bool neg = (icls[tt] != jcls);
                #pragma unroll
                for (int r = 0; r < 4; ++r) {
                    float s  = ac[tt][r];
                    float sp = softplus_poly(fmaf(40.f, s, c40[tt][r]));
                    float m  = (neg && s > threshR[tt][r]) ? 1.f : 0.f;
                    accA[tt][r] += m;
                    accB[tt][r] = fmaf(m, sp, accB[tt][r]);
                }
            }
        }

        __syncthreads();    // drains glds for jt+1; frees buf for jt+2
        buf ^= 1;
    }

    // quad shuffle-reduce (16 lanes share rows) -> float4 partial stores
    #pragma unroll
    for (int tt = 0; tt < 2; ++tt) {
        #pragma unroll
        for (int r = 0; r < 4; ++r) {
            #pragma unroll
            for (int m = 8; m >= 1; m >>= 1) {
                accA[tt][r] += __shfl_xor(accA[tt][r], m);
                accB[tt][r] += __shfl_xor(accB[tt][r], m);
            }
        }
        if (n16 == 0) {
            int base = blockIdx.y * NROWS + i0 + tt * 16 + quad * 4;
            float4 va = {accA[tt][0], accA[tt][1], accA[tt][2], accA[tt][3]};
            float4 vb = {accB[tt][0], accB[tt][1], accB[tt][2], accB[tt][3]};
            *reinterpret_cast<float4*>(&outPartA[base]) = va;
            *reinterpret_cast<float4*>(&outPartB[base]) = vb;
        }
    }
}

// 16 blocks x 256 threads; thread -> one row. Reduce cnt/nls partials ->
// rowLoss/rowInv, block-reduce 4 sums, last block combines -> out.
__global__ __launch_bounds__(256)
void finalAB_kernel(const float* __restrict__ cntPart,
                    const float* __restrict__ nlsPart,
                    const float* __restrict__ posLossA,
                    const float* __restrict__ rowPsum,
                    const float* __restrict__ rowNsum,
                    float* __restrict__ blkPart,      // 16*4 floats
                    unsigned int* __restrict__ counter,
                    float* __restrict__ out)
{
    const int t = threadIdx.x;
    const int i = blockIdx.x * 256 + t;

    float c = 0.f, n = 0.f;
    #pragma unroll
    for (int b = 0; b < NJB; ++b) {
        c += cntPart[b * NROWS + i];
        n += nlsPart[b * NROWS + i];
    }
    float loss = (c > 0.f) ? (posLossA[i] + 0.05f * n / c) : 0.f;
    float inv  = (c > 0.f) ? 0.f : 1.f;
    float pd   = rowPsum[i];
    float nd   = rowNsum[i];

    #pragma unroll
    for (int off = 32; off > 0; off >>= 1) {
        loss += __shfl_down(loss, off);
        inv  += __shfl_down(inv, off);
        pd   += __shfl_down(pd, off);
        nd   += __shfl_down(nd, off);
    }
    __shared__ float sl[4], si[4], sp[4], sq[4];
    int w = t >> 6;
    if ((t & 63) == 0) { sl[w] = loss; si[w] = inv; sp[w] = pd; sq[w] = nd; }
    __syncthreads();
    if (t == 0) {
        blkPart[blockIdx.x * 4 + 0] = sl[0] + sl[1] + sl[2] + sl[3];
        blkPart[blockIdx.x * 4 + 1] = si[0] + si[1] + si[2] + si[3];
        blkPart[blockIdx.x * 4 + 2] = sp[0] + sp[1] + sp[2] + sp[3];
        blkPart[blockIdx.x * 4 + 3] = sq[0] + sq[1] + sq[2] + sq[3];
        __threadfence();
        unsigned int old = atomicAdd(counter, 1u);
        sl[0] = (old == 15u) ? 1.f : 0.f;       // reuse LDS as flag
    }
    __syncthreads();
    if (sl[0] != 0.f && t < 64) {
        // last block: coherent read of all 64 partials (distinct addresses)
        float v = atomicAdd(&blkPart[t], 0.f);
        #pragma unroll
        for (int off = 4; off < 64; off <<= 1) v += __shfl_xor(v, off);
        // lanes 0..3 now hold totals: loss, inv, psum, nsum
        if (t == 0) out[0] = v / (float)NROWS;
        if (t == 1) out[1] = v / (float)NROWS;
        if (t == 2) out[2] = v / ((float)NROWS * (float)(KCLS - 1));
        if (t == 3) out[3] = v / ((float)NROWS * (float)(NROWS - KCLS));
    }
}

extern "C" void kernel_launch(void* const* d_in, const int* in_sizes, int n_in,
                              void* d_out, int out_size, void* d_ws, size_t ws_size,
                              hipStream_t stream)
{
    const float* X = (const float*)d_in[0];

    float* ws       = (float*)d_ws;
    float* sumPart  = ws;                                   // 32*4096
    float* sqPart   = sumPart + NJB * NROWS;                // 32*4096
    float* cntPart  = sqPart  + NJB * NROWS;                // 32*4096
    float* nlsPart  = cntPart + NJB * NROWS;                // 32*4096
    float* classSim = nlsPart + NJB * NROWS;                // 4096*8
    float* posLossA = classSim + NROWS * KCLS;              // 4096
    float* rowPsum  = posLossA + NROWS;
    float* rowNsum  = rowPsum + NROWS;
    float* blkPart  = rowNsum + NROWS;                      // 64
    unsigned int* counter = (unsigned int*)(blkPart + 64);  // 1
    unsigned short* Xf = (unsigned short*)(counter + 16);   // 2 MB
    // total ws use: ~2.4 MB; counter zeroed by convert (2 dispatches early)

    convert_kernel<<<512, 256, 0, stream>>>(X, Xf, counter);

    dim3 grid(32, 32);
    gemm_pass_kernel<1><<<grid, 256, 0, stream>>>(Xf, nullptr, nullptr,
                                                  classSim, sumPart, sqPart,
                                                  nullptr, nullptr, nullptr);

    gemm_pass_kernel<0><<<grid, 256, 0, stream>>>(Xf, sumPart, sqPart,
                                                  classSim, cntPart, nlsPart,
                                                  posLossA, rowPsum, rowNsum);

    finalAB_kernel<<<16, 256, 0, stream>>>(cntPart, nlsPart, posLossA,
                                           rowPsum, rowNsum, blkPart, counter,
                                           (float*)d_out);
}

// Round 16
// 96.528 us; speedup vs baseline: 1.0095x; 1.0095x over previous
//
#include <hip/hip_runtime.h>
#include <math.h>

// MarginDevianceLoss: N=4096, D=256, K=8, targets = i/8.
// Outputs: [loss, prec, pos_d, neg_d] fp32.
//
// R16 = R15 with the GEMM wave i-footprint widened 2 -> 4 i-tiles (64 rows/
// wave, 256 rows/block, grid 16x32): per staged B j-tile a wave now issues
// 64 MFMA vs 8 ds_read_b128 (was 16:8) -> MFMA-dominant, LDS reads/staging/
// barriers halved. A-frags cost 128 VGPRs (~200 total, still 2 waves/SIMD).
// Dispatches: convert -> gemm1 -> gemm2(+stats prologue) -> finalAB.
// Kept lessons: frag-major bf16 Xf + glds B-staging (R11); no inline fp32
// staging (R12); no big atomic fan-in / grid barriers (R7/R13).

#define NROWS 4096
#define DIM   256
#define KCLS  8
#define NJB   32     // j-blocks = partials per row
#define NT    4      // i-tiles per wave

typedef __bf16 bf16x8 __attribute__((ext_vector_type(8)));
typedef float  f32x4  __attribute__((ext_vector_type(4)));

// log(1+exp(z)) = max(z,0) + ln2 * log2(1 + exp2(-|z|*log2e));
// log2(1+u), u in (0,1], quartic fit (abs err <= ~4e-4).
__device__ __forceinline__ float softplus_poly(float z) {
    float u = __builtin_exp2f(-1.4426950408889634f * __builtin_fabsf(z));
    float p = u * (1.4426950f + u * (-0.6949650f + u * (0.3454302f + u * -0.0931600f)));
    return fmaf(p, 0.6931471805599453f, fmaxf(z, 0.f));
}

__device__ __forceinline__ unsigned int pack_bf2(float a, float b) {
    unsigned int ua = __float_as_uint(a);
    unsigned int ub = __float_as_uint(b);
    ua = (ua + 0x7FFFu + ((ua >> 16) & 1u)) >> 16;   // RNE
    ub = (ub + 0x7FFFu + ((ub >> 16) & 1u)) >> 16;
    return ua | (ub << 16);
}

__device__ __forceinline__ void glds16(const unsigned short* g, unsigned short* l) {
    // HW: each lane reads 16 B at its own g; LDS dest = uniform l + lane*16.
    __builtin_amdgcn_global_load_lds(
        (const __attribute__((address_space(1))) void*)g,
        (__attribute__((address_space(3))) void*)l, 16, 0, 0);
}

// X (fp32 row-major) -> Xf (bf16 fragment-major):
// Xf[((tile*8 + kf)*64 + lane)*8 + e] = X[tile*16 + (lane&15)][kf*32 + (lane>>4)*8 + e]
// Also zeroes the finalAB done-counter (used 2 dispatches later).
__global__ __launch_bounds__(256)
void convert_kernel(const float* __restrict__ X, unsigned short* __restrict__ Xf,
                    unsigned int* __restrict__ counter)
{
    int v = blockIdx.x * 256 + threadIdx.x;    // 131072 fragment-slices of 16 B
    if (v == 0) *counter = 0u;
    int tile = v >> 9;
    int kf   = (v >> 6) & 7;
    int lane = v & 63;
    int row  = tile * 16 + (lane & 15);
    int c4   = kf * 8 + (lane >> 4) * 2;       // col/4
    const float4* X4 = reinterpret_cast<const float4*>(X);
    float4 a = X4[row * 64 + c4];
    float4 b = X4[row * 64 + c4 + 1];
    uint4 o;
    o.x = pack_bf2(a.x, a.y);
    o.y = pack_bf2(a.z, a.w);
    o.z = pack_bf2(b.x, b.y);
    o.w = pack_bf2(b.z, b.w);
    reinterpret_cast<uint4*>(Xf)[v] = o;
}

// Grid (16,32). Block: 4 waves; wave w -> i-tiles [bx*16+w*4, +4) (64 rows,
// A cached in regs for K=256 = 128 VGPRs). All waves sweep j-tiles [by*8,+8);
// B staged via LDS (global_load_lds, double-buffered, 2 frags/wave/tile).
// PASS 1 (STATS=1): sum/sumsq epilogue + diag classSim -> float4 partials.
// PASS 2 (STATS=0): prologue computes per-row inter/thresh from pass-1
//   partials (256 rows/block, 1/thread; by==0 writes posLoss/psum/nsum),
//   then branchless filter + poly-softplus -> cnt/nls partials.
template<int STATS>
__global__ __launch_bounds__(256)
void gemm_pass_kernel(const unsigned short* __restrict__ Xf,
                      const float* __restrict__ sumPart,   // in  (pass 2)
                      const float* __restrict__ sqPart,    // in  (pass 2)
                      float* __restrict__ classSim,        // out p1 / in p2
                      float* __restrict__ outPartA,        // sumPart / cntPart
                      float* __restrict__ outPartB,        // sqPart  / nlsPart
                      float* __restrict__ posLossA,
                      float* __restrict__ rowPsum,
                      float* __restrict__ rowNsum)
{
    __shared__ __align__(16) unsigned short Bs[2][8][512];   // 2 x 8 KB
    __shared__ float interL[256], threshL[256];

    const int t    = threadIdx.x;
    const int lane = t & 63;
    const int wave = t >> 6;
    const int quad = lane >> 4;
    const int n16  = lane & 15;
    const int it0  = blockIdx.x * 16 + wave * NT;
    const int i0   = it0 * 16;
    const int j0   = blockIdx.y * 128;
    const int jt0  = blockIdx.y * 8;
    // block rows [bx*256,+256) x cols [by*128,+128): same-class pairs exist
    // iff by>>1 == bx.
    const bool diag = ((blockIdx.y >> 1) == blockIdx.x);

    // A fragments: NT i-tiles x 8 k-frags, coalesced 1-KB global loads
    bf16x8 afrag[NT][8];
    #pragma unroll
    for (int tt = 0; tt < NT; ++tt) {
        const unsigned short* ap = Xf + ((size_t)(it0 + tt) * 8) * 512 + lane * 8;
        #pragma unroll
        for (int kf = 0; kf < 8; ++kf)
            afrag[tt][kf] = *reinterpret_cast<const bf16x8*>(ap + kf * 512);
    }

    // ---- pass-2 prologue: stats for this block's 256 i-rows (1/thread) ----
    if constexpr (!STATS) {
        const int i = blockIdx.x * 256 + t;
        const int self = i & 7;
        float S = 0.f, SQ = 0.f;
        #pragma unroll
        for (int b = 0; b < NJB; ++b) {
            S  += sumPart[b * NROWS + i];
            SQ += sqPart[b * NROWS + i];
        }
        float4 c0 = reinterpret_cast<const float4*>(classSim)[i * 2];
        float4 c1 = reinterpret_cast<const float4*>(classSim)[i * 2 + 1];
        float cs[KCLS] = {c0.x, c0.y, c0.z, c0.w, c1.x, c1.y, c1.z, c1.w};
        float sii = cs[self];
        float psum = 0.f, psq = 0.f, pmin = 1e30f;
        #pragma unroll
        for (int m = 0; m < KCLS; ++m) {
            if (m != self) {
                psum += cs[m];
                psq  += cs[m] * cs[m];
                pmin  = fminf(pmin, cs[m]);
            }
        }
        const float p = (float)(KCLS - 1);            // 7
        const float mneg = (float)(NROWS - KCLS);     // 4088
        float nsum = S - psum - sii;
        float nsq  = SQ - psq - sii * sii;
        float pmean = psum / p;
        float pstd  = sqrtf(fmaxf(psq / p - pmean * pmean, 0.f));
        float nmean = nsum / mneg;
        float nstd  = sqrtf(fmaxf(nsq / mneg - nmean * nmean, 0.f));
        float inter = 0.8f * (nstd * pmean + pstd * nmean) / (pstd + nstd) + 0.1f;
        interL[t]  = inter;
        threshL[t] = pmin - 0.05f;
        if (blockIdx.y == 0) {                  // single-writer outputs
            float pl = 0.f;
            #pragma unroll
            for (int m = 0; m < KCLS; ++m) {
                if (m != self) pl += softplus_poly(-10.f * (cs[m] - inter));
            }
            posLossA[i] = pl * (0.2f / p);
            rowPsum[i]  = psum;
            rowNsum[i]  = nsum;
        }
    }

    // stage B frags for j-tile jt into buffer buf: wave w loads frags 2w,2w+1
    auto stage = [&](int buf, int jt) {
        const unsigned short* src =
            Xf + ((size_t)(jt0 + jt) * 8 + wave * 2) * 512 + lane * 8;
        glds16(src,       &Bs[buf][wave * 2][0]);
        glds16(src + 512, &Bs[buf][wave * 2 + 1][0]);
    };

    stage(0, 0);
    __syncthreads();    // drains glds AND publishes interL/threshL

    float accA[NT][4] = {};       // sI / cnt
    float accB[NT][4] = {};       // sqI / nls
    float c40[NT][4], threshR[NT][4];
    int   icls[NT];
    if constexpr (!STATS) {
        #pragma unroll
        for (int tt = 0; tt < NT; ++tt) {
            icls[tt] = (i0 + tt * 16 + quad * 4) >> 3;
            int lbase = wave * 64 + tt * 16 + quad * 4;   // local row in block
            #pragma unroll
            for (int r = 0; r < 4; ++r) {
                c40[tt][r]     = -40.f * interL[lbase + r];
                threshR[tt][r] = threshL[lbase + r];
            }
        }
    }

    int buf = 0;
    #pragma unroll 1
    for (int jt = 0; jt < 8; ++jt) {
        if (jt < 7) stage(buf ^ 1, jt + 1);

        bf16x8 bfr[8];
        #pragma unroll
        for (int kf = 0; kf < 8; ++kf)
            bfr[kf] = *reinterpret_cast<const bf16x8*>(&Bs[buf][kf][lane * 8]);

        f32x4 ac[NT];
        #pragma unroll
        for (int tt = 0; tt < NT; ++tt) ac[tt] = {0.f, 0.f, 0.f, 0.f};
        #pragma unroll
        for (int kf = 0; kf < 8; ++kf) {
            #pragma unroll
            for (int tt = 0; tt < NT; ++tt)
                ac[tt] = __builtin_amdgcn_mfma_f32_16x16x32_bf16(afrag[tt][kf], bfr[kf], ac[tt], 0, 0, 0);
        }

        if constexpr (STATS) {
            #pragma unroll
            for (int tt = 0; tt < NT; ++tt)
                #pragma unroll
                for (int r = 0; r < 4; ++r) {
                    float s = ac[tt][r];
                    accA[tt][r] += s;
                    accB[tt][r] = fmaf(s, s, accB[tt][r]);
                }
            if (diag) {                    // wave-uniform: 32/512 blocks
                int j = j0 + jt * 16 + n16;
                #pragma unroll
                for (int tt = 0; tt < NT; ++tt)
                    #pragma unroll
                    for (int r = 0; r < 4; ++r) {
                        int i = i0 + tt * 16 + quad * 4 + r;
                        if (((i ^ j) >> 3) == 0)
                            classSim[i * KCLS + (j & 7)] = ac[tt][r];
                    }
            }
        } else {
            const int jcls = (j0 + jt * 16 + n16) >> 3;
            #pragma unroll
            for (int tt = 0; tt < NT; ++tt) {
                const bool neg = (icls[tt] != jcls);
                #pragma unroll
                for (int r = 0; r < 4; ++r) {
                    float s  = ac[tt][r];
                    float sp = softplus_poly(fmaf(40.f, s, c40[tt][r]));
                    float m  = (neg && s > threshR[tt][r]) ? 1.f : 0.f;
                    accA[tt][r] += m;
                    accB[tt][r] = fmaf(m, sp, accB[tt][r]);
                }
            }
        }

        __syncthreads();    // drains glds for jt+1; frees buf for jt+2
        buf ^= 1;
    }

    // quad shuffle-reduce (16 lanes share rows) -> float4 partial stores
    #pragma unroll
    for (int tt = 0; tt < NT; ++tt) {
        #pragma unroll
        for (int r = 0; r < 4; ++r) {
            #pragma unroll
            for (int m = 8; m >= 1; m >>= 1) {
                accA[tt][r] += __shfl_xor(accA[tt][r], m);
                accB[tt][r] += __shfl_xor(accB[tt][r], m);
            }
        }
        if (n16 == 0) {
            int base = blockIdx.y * NROWS + i0 + tt * 16 + quad * 4;
            float4 va = {accA[tt][0], accA[tt][1], accA[tt][2], accA[tt][3]};
            float4 vb = {accB[tt][0], accB[tt][1], accB[tt][2], accB[tt][3]};
            *reinterpret_cast<float4*>(&outPartA[base]) = va;
            *reinterpret_cast<float4*>(&outPartB[base]) = vb;
        }
    }
}

// 16 blocks x 256 threads; thread -> one row. Reduce cnt/nls partials ->
// rowLoss/rowInv, block-reduce 4 sums, last block combines -> out.
__global__ __launch_bounds__(256)
void finalAB_kernel(const float* __restrict__ cntPart,
                    const float* __restrict__ nlsPart,
                    const float* __restrict__ posLossA,
                    const float* __restrict__ rowPsum,
                    const float* __restrict__ rowNsum,
                    float* __restrict__ blkPart,      // 16*4 floats
                    unsigned int* __restrict__ counter,
                    float* __restrict__ out)
{
    const int t = threadIdx.x;
    const int i = blockIdx.x * 256 + t;

    float c = 0.f, n = 0.f;
    #pragma unroll
    for (int b = 0; b < NJB; ++b) {
        c += cntPart[b * NROWS + i];
        n += nlsPart[b * NROWS + i];
    }
    float loss = (c > 0.f) ? (posLossA[i] + 0.05f * n / c) : 0.f;
    float inv  = (c > 0.f) ? 0.f : 1.f;
    float pd   = rowPsum[i];
    float nd   = rowNsum[i];

    #pragma unroll
    for (int off = 32; off > 0; off >>= 1) {
        loss += __shfl_down(loss, off);
        inv  += __shfl_down(inv, off);
        pd   += __shfl_down(pd, off);
        nd   += __shfl_down(nd, off);
    }
    __shared__ float sl[4], si[4], sp[4], sq[4];
    int w = t >> 6;
    if ((t & 63) == 0) { sl[w] = loss; si[w] = inv; sp[w] = pd; sq[w] = nd; }
    __syncthreads();
    if (t == 0) {
        blkPart[blockIdx.x * 4 + 0] = sl[0] + sl[1] + sl[2] + sl[3];
        blkPart[blockIdx.x * 4 + 1] = si[0] + si[1] + si[2] + si[3];
        blkPart[blockIdx.x * 4 + 2] = sp[0] + sp[1] + sp[2] + sp[3];
        blkPart[blockIdx.x * 4 + 3] = sq[0] + sq[1] + sq[2] + sq[3];
        __threadfence();
        unsigned int old = atomicAdd(counter, 1u);
        sl[0] = (old == 15u) ? 1.f : 0.f;       // reuse LDS as flag
    }
    __syncthreads();
    if (sl[0] != 0.f && t < 64) {
        // last block: coherent read of all 64 partials (distinct addresses)
        float v = atomicAdd(&blkPart[t], 0.f);
        #pragma unroll
        for (int off = 4; off < 64; off <<= 1) v += __shfl_xor(v, off);
        // lanes 0..3 now hold totals: loss, inv, psum, nsum
        if (t == 0) out[0] = v / (float)NROWS;
        if (t == 1) out[1] = v / (float)NROWS;
        if (t == 2) out[2] = v / ((float)NROWS * (float)(KCLS - 1));
        if (t == 3) out[3] = v / ((float)NROWS * (float)(NROWS - KCLS));
    }
}

extern "C" void kernel_launch(void* const* d_in, const int* in_sizes, int n_in,
                              void* d_out, int out_size, void* d_ws, size_t ws_size,
                              hipStream_t stream)
{
    const float* X = (const float*)d_in[0];

    float* ws       = (float*)d_ws;
    float* sumPart  = ws;                                   // 32*4096
    float* sqPart   = sumPart + NJB * NROWS;                // 32*4096
    float* cntPart  = sqPart  + NJB * NROWS;                // 32*4096
    float* nlsPart  = cntPart + NJB * NROWS;                // 32*4096
    float* classSim = nlsPart + NJB * NROWS;                // 4096*8
    float* posLossA = classSim + NROWS * KCLS;              // 4096
    float* rowPsum  = posLossA + NROWS;
    float* rowNsum  = rowPsum + NROWS;
    float* blkPart  = rowNsum + NROWS;                      // 64
    unsigned int* counter = (unsigned int*)(blkPart + 64);  // 1
    unsigned short* Xf = (unsigned short*)(counter + 16);   // 2 MB
    // total ws use: ~2.4 MB; counter zeroed by convert (2 dispatches early)

    convert_kernel<<<512, 256, 0, stream>>>(X, Xf, counter);

    dim3 grid(16, 32);
    gemm_pass_kernel<1><<<grid, 256, 0, stream>>>(Xf, nullptr, nullptr,
                                                  classSim, sumPart, sqPart,
                                                  nullptr, nullptr, nullptr);

    gemm_pass_kernel<0><<<grid, 256, 0, stream>>>(Xf, sumPart, sqPart,
                                                  classSim, cntPart, nlsPart,
                                                  posLossA, rowPsum, rowNsum);

    finalAB_kernel<<<16, 256, 0, stream>>>(cntPart, nlsPart, posLossA,
                                           rowPsum, rowNsum, blkPart, counter,
                                           (float*)d_out);
}